// Round 8
// baseline (204.098 us; speedup 1.0000x reference)
//
#include <hip/hip_runtime.h>
#include <hip/hip_bf16.h>
#include <cstdint>
#include <cstddef>

#define Bq 4
#define Sq 2048
#define Dq 1024
#define Hq 16
#define HSq 64
#define Kc 1024

typedef short short8 __attribute__((ext_vector_type(8)));
typedef float f32x4 __attribute__((ext_vector_type(4)));

__device__ __forceinline__ unsigned short f2bf(float f){
  __hip_bfloat16 h = __float2bfloat16(f);
  return __builtin_bit_cast(unsigned short, h);
}

// HW 2^x (single v_exp_f32, ~1ulp)
__device__ __forceinline__ float exp2hw(float x){
  float r;
  asm("v_exp_f32 %0, %1" : "=v"(r) : "v"(x));
  return r;
}
// pack two f32 -> two bf16 (RNE)
__device__ __forceinline__ unsigned cvtpk(float lo, float hi){
  unsigned r;
  asm("v_cvt_pk_bf16_f32 %0, %1, %2" : "=v"(r) : "v"(lo), "v"(hi));
  return r;
}
__device__ __forceinline__ float rcphw(float x){
  float r;
  asm("v_rcp_f32 %0, %1" : "=v"(r) : "v"(x));
  return r;
}

__device__ __forceinline__ void gl_lds16(const void* g, void* l){
  __builtin_amdgcn_global_load_lds((const __attribute__((address_space(1))) void*)(g),
                                   (__attribute__((address_space(3))) void*)(l), 16, 0, 0);
}

// ---------------- 3x LayerNorm (fp32 in) -> bf16 out, one dispatch ----------------
__global__ __launch_bounds__(256) void ln3_kernel(const float* __restrict__ v,
                                                  const float* __restrict__ k,
                                                  const float* __restrict__ q,
                                                  const float* __restrict__ g,
                                                  const float* __restrict__ bta,
                                                  short* __restrict__ vo,
                                                  short* __restrict__ ko,
                                                  short* __restrict__ qo){
  const int which = blockIdx.y;
  const float* x = (which==0) ? v : (which==1) ? k : q;
  short* out     = (which==0) ? vo : (which==1) ? ko : qo;
  const int row = blockIdx.x;
  const float* xr = x + (size_t)row * Dq;
  const int t = threadIdx.x;
  float4 vv = reinterpret_cast<const float4*>(xr)[t];
  float s  = vv.x + vv.y + vv.z + vv.w;
  float ss = vv.x*vv.x + vv.y*vv.y + vv.z*vv.z + vv.w*vv.w;
  #pragma unroll
  for (int o = 32; o >= 1; o >>= 1){ s += __shfl_xor(s, o); ss += __shfl_xor(ss, o); }
  __shared__ float red[8];
  const int wid = t >> 6;
  if ((t & 63) == 0){ red[wid] = s; red[4+wid] = ss; }
  __syncthreads();
  s  = red[0]+red[1]+red[2]+red[3];
  ss = red[4]+red[5]+red[6]+red[7];
  const float mu   = s * (1.0f/Dq);
  const float var  = ss * (1.0f/Dq) - mu*mu;
  const float rstd = rsqrtf(var + 1e-5f);
  float4 gv = reinterpret_cast<const float4*>(g)[t];
  float4 bv = reinterpret_cast<const float4*>(bta)[t];
  ushort4 o4;
  o4.x = f2bf((vv.x-mu)*rstd*gv.x + bv.x);
  o4.y = f2bf((vv.y-mu)*rstd*gv.y + bv.y);
  o4.z = f2bf((vv.z-mu)*rstd*gv.z + bv.z);
  o4.w = f2bf((vv.w-mu)*rstd*gv.w + bv.w);
  reinterpret_cast<ushort4*>(out + (size_t)row*Dq)[t] = o4;
}

// ---------------- fp32 -> bf16 cast (Wp row-major == B^T layout) ----------------
__global__ __launch_bounds__(256) void cvt_kernel(const float* __restrict__ in,
                                                  short* __restrict__ out, int n4){
  int i = blockIdx.x*256 + threadIdx.x;
  if (i < n4){
    float4 v = reinterpret_cast<const float4*>(in)[i];
    ushort4 o; o.x=f2bf(v.x); o.y=f2bf(v.y); o.z=f2bf(v.z); o.w=f2bf(v.w);
    reinterpret_cast<ushort4*>(out)[i] = o;
  }
}

// W [H][1024][64] fp32 -> WT [h*64+e][1024] bf16, all three in one dispatch.
// z==0 (Wq) is pre-scaled by D^-0.5 * log2(e)  (folds softmax scale into Q).
__global__ __launch_bounds__(256) void trcvt3_kernel(const float* __restrict__ Wq,
                                                     const float* __restrict__ Wk,
                                                     const float* __restrict__ Wv,
                                                     short* __restrict__ wqt,
                                                     short* __restrict__ wkt,
                                                     short* __restrict__ wvt){
  const int z = blockIdx.z;
  const float* Wsrc = (z==0) ? Wq : (z==1) ? Wk : Wv;
  short* Wdst       = (z==0) ? wqt : (z==1) ? wkt : wvt;
  const float scl   = (z==0) ? (0.03125f * 1.44269504f) : 1.0f;
  const int h = blockIdx.y, kt = blockIdx.x, tid = threadIdx.x;
  __shared__ short t[64][68];
  const float* src = Wsrc + ((size_t)h*Kc + (size_t)kt*64) * HSq;
  #pragma unroll
  for (int c=0;c<4;c++){
    int lin = c*256 + tid;
    int kr = lin >> 4;
    int e4 = (lin & 15) * 4;
    float4 vv = *reinterpret_cast<const float4*>(&src[(size_t)kr*HSq + e4]);
    t[e4+0][kr] = (short)f2bf(vv.x*scl);
    t[e4+1][kr] = (short)f2bf(vv.y*scl);
    t[e4+2][kr] = (short)f2bf(vv.z*scl);
    t[e4+3][kr] = (short)f2bf(vv.w*scl);
  }
  __syncthreads();
  short* dst = Wdst + (size_t)h*HSq*Kc + (size_t)kt*64;
  #pragma unroll
  for (int c=0;c<4;c++){
    int lin = c*256 + tid;
    int er = lin >> 4;
    int k4 = (lin & 15) * 4;
    ushort4 o;
    o.x = (unsigned short)t[er][k4+0];
    o.y = (unsigned short)t[er][k4+1];
    o.z = (unsigned short)t[er][k4+2];
    o.w = (unsigned short)t[er][k4+3];
    *reinterpret_cast<ushort4*>(&dst[(size_t)er*Kc + k4]) = o;
  }
}

// ---------------- fused Q/K/V projection: 256x256 tile, 8 waves, counted-vmcnt ----
// grid (128, 3). bm = i>>2, bn = i&3 (XCD x keeps one B n-panel L2-resident).
// Double-buffered 128 KB LDS; per K-tile: 4 phases {stage 1 half-tile || ds_read
// 2 m-frags || 16 MFMA}; boundary = s_waitcnt vmcnt(2) + raw s_barrier (loads for
// tile t+1 stay in flight across tile t's compute -- no drains in the main loop).
__global__ __launch_bounds__(512, 2) void proj3_kernel(
    const short* __restrict__ qn, const short* __restrict__ kn, const short* __restrict__ vn,
    const short* __restrict__ wqt, const short* __restrict__ wkt, const short* __restrict__ wvt,
    short* __restrict__ qh, short* __restrict__ kh, short* __restrict__ vhT)
{
  const int z = blockIdx.y;
  const short* A  = (z==0) ? qn  : (z==1) ? kn  : vn;
  const short* BT = (z==0) ? wqt : (z==1) ? wkt : wvt;

  const int i = blockIdx.x;
  const int bm = i >> 2, bn = i & 3;
  const int m0 = bm * 256;
  const int n0c = bn * 256;
  const int tid = threadIdx.x;
  const int lane = tid & 63, w = tid >> 6;       // 8 waves
  const int wm = w >> 2, wn = w & 3;             // 2M x 4N
  const int fr = lane & 15, fg = lane >> 4;

  __shared__ short As[2][256*64];   // 64 KB  [buf][row][64 cols], chunk-swizzled
  __shared__ short Bs[2][256*64];   // 64 KB

  f32x4 acc[8][4] = {};

  // staging geometry: wave-uniform LDS dest (gl_lds16 writes base + lane*16);
  // per-lane swizzled global source. Wave w, call j covers rows 16w+8j..+8.
  const int l8 = lane >> 3;                          // 0..7
  const int sswz = ((lane & 7) ^ l8) << 4;           // src chunk = lds chunk ^ (row&7)
  const char* aRow = (const char*)(A  + (size_t)(m0  + w*16 + l8)*Kc) + sswz;
  const char* bRow = (const char*)(BT + (size_t)(n0c + w*16 + l8)*Kc) + sswz;

  // hh: 0=A half0, 1=A half1, 2=B half0, 3=B half1 (half = 128 rows)
  auto stage_half = [&](int buf, int kt, int hh){
    const char* s = (hh < 2 ? aRow : bRow) + (size_t)(hh & 1)*262144 + (size_t)kt*128;
    char* d = (char*)(hh < 2 ? (void*)As : (void*)Bs) + buf*32768 + (hh & 1)*16384 + w*2048;
    gl_lds16(s,         d);
    gl_lds16(s + 16384, d + 1024);   // +8 rows
  };

  // prologue: K-tile 0 -> buf 0 (8 loads in flight)
  #pragma unroll
  for (int hh=0; hh<4; ++hh) stage_half(0, 0, hh);

  short8 bfr[4][2];
  int cur = 0;
  for (int t = 0; t < Kc/64; ++t){
    const bool hasNext = (t < Kc/64 - 1);
    #pragma unroll
    for (int p=0; p<4; ++p){
      if (hasNext) stage_half(cur^1, t+1, p);
      if (p == 0){
        if (hasNext) asm volatile("s_waitcnt vmcnt(2)" ::: "memory");
        else         asm volatile("s_waitcnt vmcnt(0)" ::: "memory");
        __builtin_amdgcn_s_barrier();
        __builtin_amdgcn_sched_barrier(0);
        #pragma unroll
        for (int nr=0; nr<4; ++nr){
          int row = wn*64 + nr*16 + fr;
          #pragma unroll
          for (int kk=0; kk<2; ++kk){
            int byt = cur*32768 + row*128 + (((kk*4 + fg) ^ (row & 7)) << 4);
            bfr[nr][kk] = *reinterpret_cast<const short8*>((const char*)Bs + byt);
          }
        }
      }
      short8 af[2][2];
      #pragma unroll
      for (int mm=0; mm<2; ++mm){
        int row = wm*128 + (p*2 + mm)*16 + fr;
        #pragma unroll
        for (int kk=0; kk<2; ++kk){
          int byt = cur*32768 + row*128 + (((kk*4 + fg) ^ (row & 7)) << 4);
          af[mm][kk] = *reinterpret_cast<const short8*>((const char*)As + byt);
        }
      }
      __builtin_amdgcn_s_setprio(1);
      #pragma unroll
      for (int kk=0; kk<2; ++kk)
        #pragma unroll
        for (int mm=0; mm<2; ++mm)
          #pragma unroll
          for (int nr=0; nr<4; ++nr)
            acc[p*2+mm][nr] = __builtin_amdgcn_mfma_f32_16x16x32_bf16(af[mm][kk], bfr[nr][kk], acc[p*2+mm][nr], 0, 0, 0);
      __builtin_amdgcn_s_setprio(0);
    }
    __builtin_amdgcn_sched_barrier(0);
    __builtin_amdgcn_s_barrier();    // all reads of buf cur done -> next iter stages into it
    cur ^= 1;
  }

  if (z == 2){
    #pragma unroll
    for (int mr=0; mr<8; ++mr){
      #pragma unroll
      for (int nr=0; nr<4; ++nr){
        int col = n0c + wn*64 + nr*16 + fr;
        int h = col >> 6, e = col & 63;
        int R = m0 + wm*128 + mr*16 + fg*4;
        int bb = R >> 11, sPos = R & (Sq-1);
        uint2 o;
        o.x = cvtpk(acc[mr][nr][0], acc[mr][nr][1]);
        o.y = cvtpk(acc[mr][nr][2], acc[mr][nr][3]);
        *reinterpret_cast<uint2*>(&vhT[(((size_t)bb*Hq + h)*HSq + e)*Sq + sPos]) = o;
      }
    }
  } else {
    short* outb = z ? kh : qh;
    #pragma unroll
    for (int mr=0; mr<8; ++mr){
      #pragma unroll
      for (int nr=0; nr<4; ++nr){
        int col = n0c + wn*64 + nr*16 + fr;
        int h = col >> 6, e = col & 63;
        #pragma unroll
        for (int r=0; r<4; ++r){
          int R = m0 + wm*128 + mr*16 + fg*4 + r;
          int bb = R >> 11, sPos = R & (Sq-1);
          outb[(((size_t)bb*Hq + h)*Sq + sPos)*HSq + e] = (short)f2bf(acc[mr][nr][r]);
        }
      }
    }
  }
}

// ---------------- output projection GEMM (fp32 out + bias), 128x128 ----------------
__global__ __launch_bounds__(256) void gemmo_kernel(
    const short* __restrict__ A,
    const short* __restrict__ BT,
    const float* __restrict__ bias,
    float* __restrict__ outf)
{
  const int bid = blockIdx.x;
  const int c8_ = bid & 7, j = bid >> 3;
  const int bm = c8_*8 + (j & 7), bn = j >> 3;
  const int m0 = bm * 128;
  const int n0c = bn * 128;
  const int tid = threadIdx.x;
  const int lane = tid & 63, w = tid >> 6;
  const int wm = w >> 1, wn = w & 1;
  const int fr = lane & 15, fg = lane >> 4;

  __shared__ short As[128*64];
  __shared__ short Bs[128*64];

  f32x4 acc[4][4] = {};

  const int rowT = tid >> 3;
  const int inb  = (tid & 7) * 16;

  for (int kt = 0; kt < Kc/64; ++kt){
    const int k0 = kt*64;
    #pragma unroll
    for (int c=0;c<4;c++){
      int row = c*32 + rowT;
      int src = inb ^ ((row & 7) << 4);
      gl_lds16((const char*)(A  + (size_t)(m0  + row)*Kc + k0) + src,
               (char*)As + c*4096 + w*1024);
      gl_lds16((const char*)(BT + (size_t)(n0c + row)*Kc + k0) + src,
               (char*)Bs + c*4096 + w*1024);
    }
    __syncthreads();
    #pragma unroll
    for (int kk=0;kk<2;kk++){
      short8 af[4], bf8[4];
      #pragma unroll
      for (int mr=0;mr<4;mr++){
        int row = wm*64 + mr*16 + fr;
        int byt = row*128 + ((kk*64 + fg*16) ^ ((row & 7) << 4));
        af[mr] = *reinterpret_cast<const short8*>((const char*)As + byt);
      }
      #pragma unroll
      for (int nr=0;nr<4;nr++){
        int row = wn*64 + nr*16 + fr;
        int byt = row*128 + ((kk*64 + fg*16) ^ ((row & 7) << 4));
        bf8[nr] = *reinterpret_cast<const short8*>((const char*)Bs + byt);
      }
      #pragma unroll
      for (int mr=0;mr<4;mr++)
        #pragma unroll
        for (int nr=0;nr<4;nr++)
          acc[mr][nr] = __builtin_amdgcn_mfma_f32_16x16x32_bf16(af[mr], bf8[nr], acc[mr][nr], 0, 0, 0);
    }
    __syncthreads();
  }

  #pragma unroll
  for (int mr=0;mr<4;mr++){
    #pragma unroll
    for (int nr=0;nr<4;nr++){
      int col = n0c + wn*64 + nr*16 + fr;
      #pragma unroll
      for (int r=0;r<4;r++){
        int R = m0 + wm*64 + mr*16 + fg*4 + r;
        outf[(size_t)R*Dq + col] = acc[mr][nr][r] + bias[col];
      }
    }
  }
}

// ---------------- flash attention (causal), swapped-MFMA ----------------
__global__ __launch_bounds__(256, 4) void attn_kernel(
    const short* __restrict__ qh, const short* __restrict__ kh,
    const short* __restrict__ vhT, short* __restrict__ attO)
{
  const int bid = blockIdx.x;
  const int qt  = 15 - (bid >> 6);
  const int g   = bid & 63;
  const int h = g & 15, b = g >> 4;
  const short* Q  = qh  + (((size_t)b*Hq + h)*Sq)*HSq;
  const short* K  = kh  + (((size_t)b*Hq + h)*Sq)*HSq;
  const short* VT = vhT + (((size_t)b*Hq + h)*HSq)*Sq;   // [e][s]
  const int tid = threadIdx.x, w = tid >> 6, lane = tid & 63;
  const int fr = lane & 15, fg = lane >> 4;

  __shared__ short KsB[2][64*64];     // [kv][d], source pre-swizzled, LDS linear
  __shared__ short VtB[2][64*64];     // [e][kv]
  __shared__ short Ps[4][32][76];     // per-wave P [q_local][k_local], conflict-free

  const int qbase = qt * 128;
  const int nkv = 2*qt + 2;

  const int sRow = tid >> 3;
  const int swz  = ((tid & 7) << 4) ^ ((sRow & 7) << 4);
  const char* pK = (const char*)K  + (size_t)sRow*128      + swz;
  const char* pV = (const char*)VT + (size_t)sRow*(Sq*2)   + swz;

  short8 qa[2][2];
  #pragma unroll
  for (int mr=0;mr<2;mr++){
    const int qrow = qbase + w*32 + mr*16 + fr;
    #pragma unroll
    for (int kk=0;kk<2;kk++)
      qa[mr][kk] = *reinterpret_cast<const short8*>(&Q[(size_t)qrow*HSq + kk*32 + 8*fg]);
  }

  f32x4 accO[2][4] = {};      // [mr(q-block)][n0(e-block)], lane: e=fg*4+r, q=fr
  float lsum[2] = {0.0f, 0.0f};

  #pragma unroll
  for (int c=0;c<2;c++){
    gl_lds16(pK + c*4096,   (char*)KsB[0] + c*4096 + w*1024);
    gl_lds16(pV + c*131072, (char*)VtB[0] + c*4096 + w*1024);
  }
  __syncthreads();

  int buf = 0;
  for (int kt = 0; kt < nkv; ++kt){
    if (kt+1 < nkv){
      const char* nK = pK + (size_t)(kt+1)*8192;
      const char* nV = pV + (size_t)(kt+1)*128;
      #pragma unroll
      for (int c=0;c<2;c++){
        gl_lds16(nK + c*4096,   (char*)KsB[buf^1] + c*4096 + w*1024);
        gl_lds16(nV + c*131072, (char*)VtB[buf^1] + c*4096 + w*1024);
      }
    }

    // ---- S^T = K Q^T : lane holds k = n0*16+fg*4+r, q = mr*16+fr
    f32x4 sfr[2][4] = {};
    __builtin_amdgcn_s_setprio(1);
    #pragma unroll
    for (int kk=0;kk<2;kk++){
      short8 kb[4];
      #pragma unroll
      for (int n0=0;n0<4;n0++){
        int row = n0*16 + fr;
        int byt = row*128 + ((((kk*4+fg) ^ (row & 7))) << 4);
        kb[n0] = *reinterpret_cast<const short8*>((const char*)KsB[buf] + byt);
      }
      #pragma unroll
      for (int mr=0;mr<2;mr++)
        #pragma unroll
        for (int n0=0;n0<4;n0++)
          sfr[mr][n0] = __builtin_amdgcn_mfma_f32_16x16x32_bf16(kb[n0], qa[mr][kk], sfr[mr][n0], 0, 0, 0);
    }
    __builtin_amdgcn_s_setprio(0);

    // ---- softmax-lite: p = 2^s (HW exp), mask on diagonal tiles, pk-pack to LDS
    #pragma unroll
    for (int mr=0;mr<2;mr++){
      const int qr = qbase + w*32 + mr*16 + fr;
      const bool needmask = (kt*64 + 63) > (qbase + w*32 + mr*16);
      #pragma unroll
      for (int n0=0;n0<4;n0++){
        float p0 = exp2hw(sfr[mr][n0][0]);
        float p1 = exp2hw(sfr[mr][n0][1]);
        float p2 = exp2hw(sfr[mr][n0][2]);
        float p3 = exp2hw(sfr[mr][n0][3]);
        if (needmask){
          int kc = kt*64 + n0*16 + fg*4;
          if (kc+0 > qr) p0 = 0.0f;
          if (kc+1 > qr) p1 = 0.0f;
          if (kc+2 > qr) p2 = 0.0f;
          if (kc+3 > qr) p3 = 0.0f;
        }
        lsum[mr] += (p0+p1)+(p2+p3);
        uint2 u;
        u.x = cvtpk(p0, p1);
        u.y = cvtpk(p2, p3);
        *reinterpret_cast<uint2*>(&Ps[w][mr*16 + fr][n0*16 + fg*4]) = u;
      }
    }

    // ---- O^T += V^T P
    __builtin_amdgcn_s_setprio(1);
    #pragma unroll
    for (int kk=0;kk<2;kk++){
      short8 pa[2], vb[4];
      #pragma unroll
      for (int mr=0;mr<2;mr++)
        pa[mr] = *reinterpret_cast<short8*>(&Ps[w][mr*16 + fr][kk*32 + 8*fg]);
      #pragma unroll
      for (int n0=0;n0<4;n0++){
        int row = n0*16 + fr;
        int byt = row*128 + ((((kk*4+fg) ^ (row & 7))) << 4);
        vb[n0] = *reinterpret_cast<const short8*>((const char*)VtB[buf] + byt);
      }
      #pragma unroll
      for (int mr=0;mr<2;mr++)
        #pragma unroll
        for (int n0=0;n0<4;n0++)
          accO[mr][n0] = __builtin_amdgcn_mfma_f32_16x16x32_bf16(vb[n0], pa[mr], accO[mr][n0], 0, 0, 0);
    }
    __builtin_amdgcn_s_setprio(0);

    __syncthreads();
    buf ^= 1;
  }

  // ---- epilogue: reduce lsum across fg groups (same q = same fr), pk-packed b64
  #pragma unroll
  for (int mr=0;mr<2;mr++){
    float l = lsum[mr];
    l += __shfl_xor(l, 16);
    l += __shfl_xor(l, 32);
    float inv = rcphw(l);
    const int qr = qbase + w*32 + mr*16 + fr;
    short* orow = attO + ((size_t)b*Sq + qr)*Dq + h*HSq;
    #pragma unroll
    for (int n0=0;n0<4;n0++){
      uint2 u;
      u.x = cvtpk(accO[mr][n0][0] * inv, accO[mr][n0][1] * inv);
      u.y = cvtpk(accO[mr][n0][2] * inv, accO[mr][n0][3] * inv);
      *reinterpret_cast<uint2*>(&orow[n0*16 + fg*4]) = u;
    }
  }
}

extern "C" void kernel_launch(void* const* d_in, const int* in_sizes, int n_in,
                              void* d_out, int out_size, void* d_ws, size_t ws_size,
                              hipStream_t stream){
  const float* v_in = (const float*)d_in[0];
  const float* k_in = (const float*)d_in[1];
  const float* q_in = (const float*)d_in[2];
  const float* ln_g = (const float*)d_in[4];
  const float* ln_b = (const float*)d_in[5];
  const float* Wq   = (const float*)d_in[6];
  const float* Wk   = (const float*)d_in[7];
  const float* Wv   = (const float*)d_in[8];
  const float* Wp   = (const float*)d_in[9];
  const float* bp   = (const float*)d_in[10];
  float* out = (float*)d_out;

  char* ws = (char*)d_ws;
  const size_t BSD  = (size_t)Bq*Sq*Dq;
  const size_t BSD2 = BSD * 2;
  short* vn  = (short*)(ws);
  short* kn  = (short*)(ws + BSD2);
  short* qn  = (short*)(ws + 2*BSD2);
  short* wqt = (short*)(ws + 3*BSD2);
  short* wkt = (short*)(ws + 3*BSD2 + 2097152);
  short* wvt = (short*)(ws + 3*BSD2 + 2*2097152);
  short* wpb = (short*)(ws + 3*BSD2 + 3*2097152);
  short* qh  = (short*)(ws + 3*BSD2 + 4*2097152);
  short* kh  = qh + BSD;
  short* vhT = kh + BSD;
  short* attO = vn;   // vn dead after v-projection

  ln3_kernel<<<dim3(Bq*Sq, 3), 256, 0, stream>>>(v_in, k_in, q_in, ln_g, ln_b, vn, kn, qn);

  trcvt3_kernel<<<dim3(16, Hq, 3), 256, 0, stream>>>(Wq, Wk, Wv, wqt, wkt, wvt);
  cvt_kernel<<<1024, 256, 0, stream>>>(Wp, wpb, 262144);

  proj3_kernel<<<dim3(128, 3), 512, 0, stream>>>(qn, kn, vn, wqt, wkt, wvt, qh, kh, vhT);

  attn_kernel<<<1024, 256, 0, stream>>>(qh, kh, vhT, attO);

  gemmo_kernel<<<512, 256, 0, stream>>>(attO, wpb, bp, out);
}

// Round 9
// 189.081 us; speedup vs baseline: 1.0794x; 1.0794x over previous
//
#include <hip/hip_runtime.h>
#include <hip/hip_bf16.h>
#include <cstdint>
#include <cstddef>

#define Bq 4
#define Sq 2048
#define Dq 1024
#define Hq 16
#define HSq 64
#define Kc 1024

typedef short short8 __attribute__((ext_vector_type(8)));
typedef float f32x4 __attribute__((ext_vector_type(4)));

__device__ __forceinline__ unsigned short f2bf(float f){
  __hip_bfloat16 h = __float2bfloat16(f);
  return __builtin_bit_cast(unsigned short, h);
}

// HW 2^x (single v_exp_f32, ~1ulp)
__device__ __forceinline__ float exp2hw(float x){
  float r;
  asm("v_exp_f32 %0, %1" : "=v"(r) : "v"(x));
  return r;
}
// pack two f32 -> two bf16 (RNE)
__device__ __forceinline__ unsigned cvtpk(float lo, float hi){
  unsigned r;
  asm("v_cvt_pk_bf16_f32 %0, %1, %2" : "=v"(r) : "v"(lo), "v"(hi));
  return r;
}
__device__ __forceinline__ float rcphw(float x){
  float r;
  asm("v_rcp_f32 %0, %1" : "=v"(r) : "v"(x));
  return r;
}

__device__ __forceinline__ void gl_lds16(const void* g, void* l){
  __builtin_amdgcn_global_load_lds((const __attribute__((address_space(1))) void*)(g),
                                   (__attribute__((address_space(3))) void*)(l), 16, 0, 0);
}

// ---------------- 3x LayerNorm (fp32 in) -> bf16 out, one dispatch ----------------
__global__ __launch_bounds__(256) void ln3_kernel(const float* __restrict__ v,
                                                  const float* __restrict__ k,
                                                  const float* __restrict__ q,
                                                  const float* __restrict__ g,
                                                  const float* __restrict__ bta,
                                                  short* __restrict__ vo,
                                                  short* __restrict__ ko,
                                                  short* __restrict__ qo){
  const int which = blockIdx.y;
  const float* x = (which==0) ? v : (which==1) ? k : q;
  short* out     = (which==0) ? vo : (which==1) ? ko : qo;
  const int row = blockIdx.x;
  const float* xr = x + (size_t)row * Dq;
  const int t = threadIdx.x;
  float4 vv = reinterpret_cast<const float4*>(xr)[t];
  float s  = vv.x + vv.y + vv.z + vv.w;
  float ss = vv.x*vv.x + vv.y*vv.y + vv.z*vv.z + vv.w*vv.w;
  #pragma unroll
  for (int o = 32; o >= 1; o >>= 1){ s += __shfl_xor(s, o); ss += __shfl_xor(ss, o); }
  __shared__ float red[8];
  const int wid = t >> 6;
  if ((t & 63) == 0){ red[wid] = s; red[4+wid] = ss; }
  __syncthreads();
  s  = red[0]+red[1]+red[2]+red[3];
  ss = red[4]+red[5]+red[6]+red[7];
  const float mu   = s * (1.0f/Dq);
  const float var  = ss * (1.0f/Dq) - mu*mu;
  const float rstd = rsqrtf(var + 1e-5f);
  float4 gv = reinterpret_cast<const float4*>(g)[t];
  float4 bv = reinterpret_cast<const float4*>(bta)[t];
  ushort4 o4;
  o4.x = f2bf((vv.x-mu)*rstd*gv.x + bv.x);
  o4.y = f2bf((vv.y-mu)*rstd*gv.y + bv.y);
  o4.z = f2bf((vv.z-mu)*rstd*gv.z + bv.z);
  o4.w = f2bf((vv.w-mu)*rstd*gv.w + bv.w);
  reinterpret_cast<ushort4*>(out + (size_t)row*Dq)[t] = o4;
}

// ---------------- fp32 -> bf16 cast (Wp row-major == B^T layout) ----------------
__global__ __launch_bounds__(256) void cvt_kernel(const float* __restrict__ in,
                                                  short* __restrict__ out, int n4){
  int i = blockIdx.x*256 + threadIdx.x;
  if (i < n4){
    float4 v = reinterpret_cast<const float4*>(in)[i];
    ushort4 o; o.x=f2bf(v.x); o.y=f2bf(v.y); o.z=f2bf(v.z); o.w=f2bf(v.w);
    reinterpret_cast<ushort4*>(out)[i] = o;
  }
}

// W [H][1024][64] fp32 -> WT [h*64+e][1024] bf16, all three in one dispatch.
// z==0 (Wq) is pre-scaled by D^-0.5 * log2(e)  (folds softmax scale into Q).
__global__ __launch_bounds__(256) void trcvt3_kernel(const float* __restrict__ Wq,
                                                     const float* __restrict__ Wk,
                                                     const float* __restrict__ Wv,
                                                     short* __restrict__ wqt,
                                                     short* __restrict__ wkt,
                                                     short* __restrict__ wvt){
  const int z = blockIdx.z;
  const float* Wsrc = (z==0) ? Wq : (z==1) ? Wk : Wv;
  short* Wdst       = (z==0) ? wqt : (z==1) ? wkt : wvt;
  const float scl   = (z==0) ? (0.03125f * 1.44269504f) : 1.0f;
  const int h = blockIdx.y, kt = blockIdx.x, tid = threadIdx.x;
  __shared__ short t[64][68];
  const float* src = Wsrc + ((size_t)h*Kc + (size_t)kt*64) * HSq;
  #pragma unroll
  for (int c=0;c<4;c++){
    int lin = c*256 + tid;
    int kr = lin >> 4;
    int e4 = (lin & 15) * 4;
    float4 vv = *reinterpret_cast<const float4*>(&src[(size_t)kr*HSq + e4]);
    t[e4+0][kr] = (short)f2bf(vv.x*scl);
    t[e4+1][kr] = (short)f2bf(vv.y*scl);
    t[e4+2][kr] = (short)f2bf(vv.z*scl);
    t[e4+3][kr] = (short)f2bf(vv.w*scl);
  }
  __syncthreads();
  short* dst = Wdst + (size_t)h*HSq*Kc + (size_t)kt*64;
  #pragma unroll
  for (int c=0;c<4;c++){
    int lin = c*256 + tid;
    int er = lin >> 4;
    int k4 = (lin & 15) * 4;
    ushort4 o;
    o.x = (unsigned short)t[er][k4+0];
    o.y = (unsigned short)t[er][k4+1];
    o.z = (unsigned short)t[er][k4+2];
    o.w = (unsigned short)t[er][k4+3];
    *reinterpret_cast<ushort4*>(&dst[(size_t)er*Kc + k4]) = o;
  }
}

// ---------------- Q/K projection GEMM, 128x128, swapped-operand epilogue ---------
// grid (512, 2): z=0 -> qh, z=1 -> kh. M-stripe XCD swizzle.
// mfma(B,A) -> lane holds 4 consecutive e per reg -> packed uint2 stores.
__global__ __launch_bounds__(256) void projqk_kernel(
    const short* __restrict__ qn, const short* __restrict__ kn,
    const short* __restrict__ wqt, const short* __restrict__ wkt,
    short* __restrict__ qh, short* __restrict__ kh)
{
  const int z = blockIdx.y;
  const short* A  = z ? kn  : qn;
  const short* BT = z ? wkt : wqt;
  short* outb     = z ? kh  : qh;

  const int bid = blockIdx.x;
  const int c8_ = bid & 7, j = bid >> 3;
  const int bm = c8_*8 + (j & 7), bn = j >> 3;
  const int m0 = bm * 128;
  const int n0c = bn * 128;
  const int tid = threadIdx.x;
  const int lane = tid & 63, w = tid >> 6;
  const int wm = w >> 1, wn = w & 1;
  const int fr = lane & 15, fg = lane >> 4;

  __shared__ short As[128*64];
  __shared__ short Bs[128*64];

  f32x4 acc[4][4] = {};

  const int rowT = tid >> 3;
  const int inb  = (tid & 7) * 16;

  for (int kt = 0; kt < Kc/64; ++kt){
    const int k0 = kt*64;
    #pragma unroll
    for (int c=0;c<4;c++){
      int row = c*32 + rowT;
      int src = inb ^ ((row & 7) << 4);
      gl_lds16((const char*)(A  + (size_t)(m0  + row)*Kc + k0) + src,
               (char*)As + c*4096 + w*1024);
      gl_lds16((const char*)(BT + (size_t)(n0c + row)*Kc + k0) + src,
               (char*)Bs + c*4096 + w*1024);
    }
    __syncthreads();
    #pragma unroll
    for (int kk=0;kk<2;kk++){
      short8 af[4], bf8[4];
      #pragma unroll
      for (int mr=0;mr<4;mr++){
        int row = wm*64 + mr*16 + fr;
        int byt = row*128 + ((kk*64 + fg*16) ^ ((row & 7) << 4));
        af[mr] = *reinterpret_cast<const short8*>((const char*)As + byt);
      }
      #pragma unroll
      for (int nr=0;nr<4;nr++){
        int row = wn*64 + nr*16 + fr;
        int byt = row*128 + ((kk*64 + fg*16) ^ ((row & 7) << 4));
        bf8[nr] = *reinterpret_cast<const short8*>((const char*)Bs + byt);
      }
      #pragma unroll
      for (int mr=0;mr<4;mr++)
        #pragma unroll
        for (int nr=0;nr<4;nr++)
          acc[mr][nr] = __builtin_amdgcn_mfma_f32_16x16x32_bf16(bf8[nr], af[mr], acc[mr][nr], 0, 0, 0);
    }
    __syncthreads();
  }

  // D^T fragment: m = ...+fr (lane-fixed), n = ...+fg*4+r (consecutive)
  #pragma unroll
  for (int mr=0;mr<4;mr++){
    const int R = m0 + wm*64 + mr*16 + fr;
    const int bb = R >> 11, sPos = R & (Sq-1);
    #pragma unroll
    for (int nr=0;nr<4;nr++){
      int colb = n0c + wn*64 + nr*16 + fg*4;
      int h = colb >> 6, e = colb & 63;
      uint2 u;
      u.x = cvtpk(acc[mr][nr][0], acc[mr][nr][1]);
      u.y = cvtpk(acc[mr][nr][2], acc[mr][nr][3]);
      *reinterpret_cast<uint2*>(&outb[(((size_t)bb*Hq + h)*Sq + sPos)*HSq + e]) = u;
    }
  }
}

// ---------------- V projection GEMM, 128x128, transposed output [B,H,E,S] --------
__global__ __launch_bounds__(256) void projv_kernel(
    const short* __restrict__ vn, const short* __restrict__ wvt,
    short* __restrict__ vhT)
{
  const int bid = blockIdx.x;
  const int c8_ = bid & 7, j = bid >> 3;
  const int bm = c8_*8 + (j & 7), bn = j >> 3;
  const int m0 = bm * 128;
  const int n0c = bn * 128;
  const int tid = threadIdx.x;
  const int lane = tid & 63, w = tid >> 6;
  const int wm = w >> 1, wn = w & 1;
  const int fr = lane & 15, fg = lane >> 4;

  __shared__ short As[128*64];
  __shared__ short Bs[128*64];

  f32x4 acc[4][4] = {};

  const int rowT = tid >> 3;
  const int inb  = (tid & 7) * 16;

  for (int kt = 0; kt < Kc/64; ++kt){
    const int k0 = kt*64;
    #pragma unroll
    for (int c=0;c<4;c++){
      int row = c*32 + rowT;
      int src = inb ^ ((row & 7) << 4);
      gl_lds16((const char*)(vn  + (size_t)(m0  + row)*Kc + k0) + src,
               (char*)As + c*4096 + w*1024);
      gl_lds16((const char*)(wvt + (size_t)(n0c + row)*Kc + k0) + src,
               (char*)Bs + c*4096 + w*1024);
    }
    __syncthreads();
    #pragma unroll
    for (int kk=0;kk<2;kk++){
      short8 af[4], bf8[4];
      #pragma unroll
      for (int mr=0;mr<4;mr++){
        int row = wm*64 + mr*16 + fr;
        int byt = row*128 + ((kk*64 + fg*16) ^ ((row & 7) << 4));
        af[mr] = *reinterpret_cast<const short8*>((const char*)As + byt);
      }
      #pragma unroll
      for (int nr=0;nr<4;nr++){
        int row = wn*64 + nr*16 + fr;
        int byt = row*128 + ((kk*64 + fg*16) ^ ((row & 7) << 4));
        bf8[nr] = *reinterpret_cast<const short8*>((const char*)Bs + byt);
      }
      #pragma unroll
      for (int mr=0;mr<4;mr++)
        #pragma unroll
        for (int nr=0;nr<4;nr++)
          acc[mr][nr] = __builtin_amdgcn_mfma_f32_16x16x32_bf16(af[mr], bf8[nr], acc[mr][nr], 0, 0, 0);
    }
    __syncthreads();
  }

  // D fragment: n(col) = ...+fr fixed, m(=sPos) = ...+fg*4+r consecutive -> [e][s] pack
  #pragma unroll
  for (int mr=0;mr<4;mr++){
    #pragma unroll
    for (int nr=0;nr<4;nr++){
      int col = n0c + wn*64 + nr*16 + fr;
      int h = col >> 6, e = col & 63;
      int R = m0 + wm*64 + mr*16 + fg*4;
      int bb = R >> 11, sPos = R & (Sq-1);
      uint2 o;
      o.x = cvtpk(acc[mr][nr][0], acc[mr][nr][1]);
      o.y = cvtpk(acc[mr][nr][2], acc[mr][nr][3]);
      *reinterpret_cast<uint2*>(&vhT[(((size_t)bb*Hq + h)*HSq + e)*Sq + sPos]) = o;
    }
  }
}

// ---------------- output projection GEMM (fp32 out + bias), swapped epilogue -----
__global__ __launch_bounds__(256) void gemmo_kernel(
    const short* __restrict__ A,
    const short* __restrict__ BT,
    const float* __restrict__ bias,
    float* __restrict__ outf)
{
  const int bid = blockIdx.x;
  const int c8_ = bid & 7, j = bid >> 3;
  const int bm = c8_*8 + (j & 7), bn = j >> 3;
  const int m0 = bm * 128;
  const int n0c = bn * 128;
  const int tid = threadIdx.x;
  const int lane = tid & 63, w = tid >> 6;
  const int wm = w >> 1, wn = w & 1;
  const int fr = lane & 15, fg = lane >> 4;

  __shared__ short As[128*64];
  __shared__ short Bs[128*64];

  f32x4 acc[4][4] = {};

  const int rowT = tid >> 3;
  const int inb  = (tid & 7) * 16;

  for (int kt = 0; kt < Kc/64; ++kt){
    const int k0 = kt*64;
    #pragma unroll
    for (int c=0;c<4;c++){
      int row = c*32 + rowT;
      int src = inb ^ ((row & 7) << 4);
      gl_lds16((const char*)(A  + (size_t)(m0  + row)*Kc + k0) + src,
               (char*)As + c*4096 + w*1024);
      gl_lds16((const char*)(BT + (size_t)(n0c + row)*Kc + k0) + src,
               (char*)Bs + c*4096 + w*1024);
    }
    __syncthreads();
    #pragma unroll
    for (int kk=0;kk<2;kk++){
      short8 af[4], bf8[4];
      #pragma unroll
      for (int mr=0;mr<4;mr++){
        int row = wm*64 + mr*16 + fr;
        int byt = row*128 + ((kk*64 + fg*16) ^ ((row & 7) << 4));
        af[mr] = *reinterpret_cast<const short8*>((const char*)As + byt);
      }
      #pragma unroll
      for (int nr=0;nr<4;nr++){
        int row = wn*64 + nr*16 + fr;
        int byt = row*128 + ((kk*64 + fg*16) ^ ((row & 7) << 4));
        bf8[nr] = *reinterpret_cast<const short8*>((const char*)Bs + byt);
      }
      #pragma unroll
      for (int mr=0;mr<4;mr++)
        #pragma unroll
        for (int nr=0;nr<4;nr++)
          acc[mr][nr] = __builtin_amdgcn_mfma_f32_16x16x32_bf16(bf8[nr], af[mr], acc[mr][nr], 0, 0, 0);
    }
    __syncthreads();
  }

  // D^T fragment: row R = ...+fr fixed, col = ...+fg*4+r consecutive -> float4 stores
  float4 bv[4];
  #pragma unroll
  for (int nr=0;nr<4;nr++)
    bv[nr] = *reinterpret_cast<const float4*>(&bias[n0c + wn*64 + nr*16 + fg*4]);
  #pragma unroll
  for (int mr=0;mr<4;mr++){
    const int R = m0 + wm*64 + mr*16 + fr;
    #pragma unroll
    for (int nr=0;nr<4;nr++){
      int colb = n0c + wn*64 + nr*16 + fg*4;
      float4 o;
      o.x = acc[mr][nr][0] + bv[nr].x;
      o.y = acc[mr][nr][1] + bv[nr].y;
      o.z = acc[mr][nr][2] + bv[nr].z;
      o.w = acc[mr][nr][3] + bv[nr].w;
      *reinterpret_cast<float4*>(&outf[(size_t)R*Dq + colb]) = o;
    }
  }
}

// ---------------- flash attention (causal), swapped-MFMA ----------------
__global__ __launch_bounds__(256, 4) void attn_kernel(
    const short* __restrict__ qh, const short* __restrict__ kh,
    const short* __restrict__ vhT, short* __restrict__ attO)
{
  const int bid = blockIdx.x;
  const int qt  = 15 - (bid >> 6);
  const int g   = bid & 63;
  const int h = g & 15, b = g >> 4;
  const short* Q  = qh  + (((size_t)b*Hq + h)*Sq)*HSq;
  const short* K  = kh  + (((size_t)b*Hq + h)*Sq)*HSq;
  const short* VT = vhT + (((size_t)b*Hq + h)*HSq)*Sq;   // [e][s]
  const int tid = threadIdx.x, w = tid >> 6, lane = tid & 63;
  const int fr = lane & 15, fg = lane >> 4;

  __shared__ short KsB[2][64*64];     // [kv][d], source pre-swizzled, LDS linear
  __shared__ short VtB[2][64*64];     // [e][kv]
  __shared__ short Ps[4][32][76];     // per-wave P [q_local][k_local], conflict-free

  const int qbase = qt * 128;
  const int nkv = 2*qt + 2;

  const int sRow = tid >> 3;
  const int swz  = ((tid & 7) << 4) ^ ((sRow & 7) << 4);
  const char* pK = (const char*)K  + (size_t)sRow*128      + swz;
  const char* pV = (const char*)VT + (size_t)sRow*(Sq*2)   + swz;

  short8 qa[2][2];
  #pragma unroll
  for (int mr=0;mr<2;mr++){
    const int qrow = qbase + w*32 + mr*16 + fr;
    #pragma unroll
    for (int kk=0;kk<2;kk++)
      qa[mr][kk] = *reinterpret_cast<const short8*>(&Q[(size_t)qrow*HSq + kk*32 + 8*fg]);
  }

  f32x4 accO[2][4] = {};      // [mr(q-block)][n0(e-block)], lane: e=fg*4+r, q=fr
  float lsum[2] = {0.0f, 0.0f};

  #pragma unroll
  for (int c=0;c<2;c++){
    gl_lds16(pK + c*4096,   (char*)KsB[0] + c*4096 + w*1024);
    gl_lds16(pV + c*131072, (char*)VtB[0] + c*4096 + w*1024);
  }
  __syncthreads();

  int buf = 0;
  for (int kt = 0; kt < nkv; ++kt){
    if (kt+1 < nkv){
      const char* nK = pK + (size_t)(kt+1)*8192;
      const char* nV = pV + (size_t)(kt+1)*128;
      #pragma unroll
      for (int c=0;c<2;c++){
        gl_lds16(nK + c*4096,   (char*)KsB[buf^1] + c*4096 + w*1024);
        gl_lds16(nV + c*131072, (char*)VtB[buf^1] + c*4096 + w*1024);
      }
    }

    // ---- S^T = K Q^T : lane holds k = n0*16+fg*4+r, q = mr*16+fr
    f32x4 sfr[2][4] = {};
    __builtin_amdgcn_s_setprio(1);
    #pragma unroll
    for (int kk=0;kk<2;kk++){
      short8 kb[4];
      #pragma unroll
      for (int n0=0;n0<4;n0++){
        int row = n0*16 + fr;
        int byt = row*128 + ((((kk*4+fg) ^ (row & 7))) << 4);
        kb[n0] = *reinterpret_cast<const short8*>((const char*)KsB[buf] + byt);
      }
      #pragma unroll
      for (int mr=0;mr<2;mr++)
        #pragma unroll
        for (int n0=0;n0<4;n0++)
          sfr[mr][n0] = __builtin_amdgcn_mfma_f32_16x16x32_bf16(kb[n0], qa[mr][kk], sfr[mr][n0], 0, 0, 0);
    }
    __builtin_amdgcn_s_setprio(0);

    // ---- softmax-lite: p = 2^s (HW exp), mask on diagonal tiles, pk-pack to LDS
    #pragma unroll
    for (int mr=0;mr<2;mr++){
      const int qr = qbase + w*32 + mr*16 + fr;
      const bool needmask = (kt*64 + 63) > (qbase + w*32 + mr*16);
      #pragma unroll
      for (int n0=0;n0<4;n0++){
        float p0 = exp2hw(sfr[mr][n0][0]);
        float p1 = exp2hw(sfr[mr][n0][1]);
        float p2 = exp2hw(sfr[mr][n0][2]);
        float p3 = exp2hw(sfr[mr][n0][3]);
        if (needmask){
          int kc = kt*64 + n0*16 + fg*4;
          if (kc+0 > qr) p0 = 0.0f;
          if (kc+1 > qr) p1 = 0.0f;
          if (kc+2 > qr) p2 = 0.0f;
          if (kc+3 > qr) p3 = 0.0f;
        }
        lsum[mr] += (p0+p1)+(p2+p3);
        uint2 u;
        u.x = cvtpk(p0, p1);
        u.y = cvtpk(p2, p3);
        *reinterpret_cast<uint2*>(&Ps[w][mr*16 + fr][n0*16 + fg*4]) = u;
      }
    }

    // ---- O^T += V^T P
    __builtin_amdgcn_s_setprio(1);
    #pragma unroll
    for (int kk=0;kk<2;kk++){
      short8 pa[2], vb[4];
      #pragma unroll
      for (int mr=0;mr<2;mr++)
        pa[mr] = *reinterpret_cast<short8*>(&Ps[w][mr*16 + fr][kk*32 + 8*fg]);
      #pragma unroll
      for (int n0=0;n0<4;n0++){
        int row = n0*16 + fr;
        int byt = row*128 + ((((kk*4+fg) ^ (row & 7))) << 4);
        vb[n0] = *reinterpret_cast<const short8*>((const char*)VtB[buf] + byt);
      }
      #pragma unroll
      for (int mr=0;mr<2;mr++)
        #pragma unroll
        for (int n0=0;n0<4;n0++)
          accO[mr][n0] = __builtin_amdgcn_mfma_f32_16x16x32_bf16(vb[n0], pa[mr], accO[mr][n0], 0, 0, 0);
    }
    __builtin_amdgcn_s_setprio(0);

    __syncthreads();
    buf ^= 1;
  }

  // ---- epilogue: reduce lsum across fg groups (same q = same fr), pk-packed b64
  #pragma unroll
  for (int mr=0;mr<2;mr++){
    float l = lsum[mr];
    l += __shfl_xor(l, 16);
    l += __shfl_xor(l, 32);
    float inv = rcphw(l);
    const int qr = qbase + w*32 + mr*16 + fr;
    short* orow = attO + ((size_t)b*Sq + qr)*Dq + h*HSq;
    #pragma unroll
    for (int n0=0;n0<4;n0++){
      uint2 u;
      u.x = cvtpk(accO[mr][n0][0] * inv, accO[mr][n0][1] * inv);
      u.y = cvtpk(accO[mr][n0][2] * inv, accO[mr][n0][3] * inv);
      *reinterpret_cast<uint2*>(&orow[n0*16 + fg*4]) = u;
    }
  }
}

extern "C" void kernel_launch(void* const* d_in, const int* in_sizes, int n_in,
                              void* d_out, int out_size, void* d_ws, size_t ws_size,
                              hipStream_t stream){
  const float* v_in = (const float*)d_in[0];
  const float* k_in = (const float*)d_in[1];
  const float* q_in = (const float*)d_in[2];
  const float* ln_g = (const float*)d_in[4];
  const float* ln_b = (const float*)d_in[5];
  const float* Wq   = (const float*)d_in[6];
  const float* Wk   = (const float*)d_in[7];
  const float* Wv   = (const float*)d_in[8];
  const float* Wp   = (const float*)d_in[9];
  const float* bp   = (const float*)d_in[10];
  float* out = (float*)d_out;

  char* ws = (char*)d_ws;
  const size_t BSD  = (size_t)Bq*Sq*Dq;
  const size_t BSD2 = BSD * 2;
  short* vn  = (short*)(ws);
  short* kn  = (short*)(ws + BSD2);
  short* qn  = (short*)(ws + 2*BSD2);
  short* wqt = (short*)(ws + 3*BSD2);
  short* wkt = (short*)(ws + 3*BSD2 + 2097152);
  short* wvt = (short*)(ws + 3*BSD2 + 2*2097152);
  short* wpb = (short*)(ws + 3*BSD2 + 3*2097152);
  short* qh  = (short*)(ws + 3*BSD2 + 4*2097152);
  short* kh  = qh + BSD;
  short* vhT = kh + BSD;
  short* attO = vn;   // vn dead after v-projection

  ln3_kernel<<<dim3(Bq*Sq, 3), 256, 0, stream>>>(v_in, k_in, q_in, ln_g, ln_b, vn, kn, qn);

  trcvt3_kernel<<<dim3(16, Hq, 3), 256, 0, stream>>>(Wq, Wk, Wv, wqt, wkt, wvt);
  cvt_kernel<<<1024, 256, 0, stream>>>(Wp, wpb, 262144);

  projqk_kernel<<<dim3(512, 2), 256, 0, stream>>>(qn, kn, wqt, wkt, qh, kh);
  projv_kernel<<<512, 256, 0, stream>>>(vn, wvt, vhT);

  attn_kernel<<<1024, 256, 0, stream>>>(qh, kh, vhT, attO);

  gemmo_kernel<<<512, 256, 0, stream>>>(attO, wpb, bp, out);
}

// Round 10
// 186.321 us; speedup vs baseline: 1.0954x; 1.0148x over previous
//
#include <hip/hip_runtime.h>
#include <hip/hip_bf16.h>
#include <cstdint>
#include <cstddef>

#define Bq 4
#define Sq 2048
#define Dq 1024
#define Hq 16
#define HSq 64
#define Kc 1024

typedef short short8 __attribute__((ext_vector_type(8)));
typedef float f32x4 __attribute__((ext_vector_type(4)));

__device__ __forceinline__ unsigned short f2bf(float f){
  __hip_bfloat16 h = __float2bfloat16(f);
  return __builtin_bit_cast(unsigned short, h);
}

// HW 2^x (single v_exp_f32, ~1ulp)
__device__ __forceinline__ float exp2hw(float x){
  float r;
  asm("v_exp_f32 %0, %1" : "=v"(r) : "v"(x));
  return r;
}
// pack two f32 -> two bf16 (RNE)
__device__ __forceinline__ unsigned cvtpk(float lo, float hi){
  unsigned r;
  asm("v_cvt_pk_bf16_f32 %0, %1, %2" : "=v"(r) : "v"(lo), "v"(hi));
  return r;
}
__device__ __forceinline__ float rcphw(float x){
  float r;
  asm("v_rcp_f32 %0, %1" : "=v"(r) : "v"(x));
  return r;
}

__device__ __forceinline__ void gl_lds16(const void* g, void* l){
  __builtin_amdgcn_global_load_lds((const __attribute__((address_space(1))) void*)(g),
                                   (__attribute__((address_space(3))) void*)(l), 16, 0, 0);
}

// ---------------- 3x LayerNorm (fp32 in) -> bf16 out, one dispatch ----------------
__global__ __launch_bounds__(256) void ln3_kernel(const float* __restrict__ v,
                                                  const float* __restrict__ k,
                                                  const float* __restrict__ q,
                                                  const float* __restrict__ g,
                                                  const float* __restrict__ bta,
                                                  short* __restrict__ vo,
                                                  short* __restrict__ ko,
                                                  short* __restrict__ qo){
  const int which = blockIdx.y;
  const float* x = (which==0) ? v : (which==1) ? k : q;
  short* out     = (which==0) ? vo : (which==1) ? ko : qo;
  const int row = blockIdx.x;
  const float* xr = x + (size_t)row * Dq;
  const int t = threadIdx.x;
  float4 vv = reinterpret_cast<const float4*>(xr)[t];
  float s  = vv.x + vv.y + vv.z + vv.w;
  float ss = vv.x*vv.x + vv.y*vv.y + vv.z*vv.z + vv.w*vv.w;
  #pragma unroll
  for (int o = 32; o >= 1; o >>= 1){ s += __shfl_xor(s, o); ss += __shfl_xor(ss, o); }
  __shared__ float red[8];
  const int wid = t >> 6;
  if ((t & 63) == 0){ red[wid] = s; red[4+wid] = ss; }
  __syncthreads();
  s  = red[0]+red[1]+red[2]+red[3];
  ss = red[4]+red[5]+red[6]+red[7];
  const float mu   = s * (1.0f/Dq);
  const float var  = ss * (1.0f/Dq) - mu*mu;
  const float rstd = rsqrtf(var + 1e-5f);
  float4 gv = reinterpret_cast<const float4*>(g)[t];
  float4 bv = reinterpret_cast<const float4*>(bta)[t];
  ushort4 o4;
  o4.x = f2bf((vv.x-mu)*rstd*gv.x + bv.x);
  o4.y = f2bf((vv.y-mu)*rstd*gv.y + bv.y);
  o4.z = f2bf((vv.z-mu)*rstd*gv.z + bv.z);
  o4.w = f2bf((vv.w-mu)*rstd*gv.w + bv.w);
  reinterpret_cast<ushort4*>(out + (size_t)row*Dq)[t] = o4;
}

// ---------------- fp32 -> bf16 cast (Wp row-major == B^T layout) ----------------
__global__ __launch_bounds__(256) void cvt_kernel(const float* __restrict__ in,
                                                  short* __restrict__ out, int n4){
  int i = blockIdx.x*256 + threadIdx.x;
  if (i < n4){
    float4 v = reinterpret_cast<const float4*>(in)[i];
    ushort4 o; o.x=f2bf(v.x); o.y=f2bf(v.y); o.z=f2bf(v.z); o.w=f2bf(v.w);
    reinterpret_cast<ushort4*>(out)[i] = o;
  }
}

// W [H][1024][64] fp32 -> WT [h*64+e][1024] bf16, all three in one dispatch.
// z==0 (Wq) is pre-scaled by D^-0.5 * log2(e)  (folds softmax scale into Q).
__global__ __launch_bounds__(256) void trcvt3_kernel(const float* __restrict__ Wq,
                                                     const float* __restrict__ Wk,
                                                     const float* __restrict__ Wv,
                                                     short* __restrict__ wqt,
                                                     short* __restrict__ wkt,
                                                     short* __restrict__ wvt){
  const int z = blockIdx.z;
  const float* Wsrc = (z==0) ? Wq : (z==1) ? Wk : Wv;
  short* Wdst       = (z==0) ? wqt : (z==1) ? wkt : wvt;
  const float scl   = (z==0) ? (0.03125f * 1.44269504f) : 1.0f;
  const int h = blockIdx.y, kt = blockIdx.x, tid = threadIdx.x;
  __shared__ short t[64][68];
  const float* src = Wsrc + ((size_t)h*Kc + (size_t)kt*64) * HSq;
  #pragma unroll
  for (int c=0;c<4;c++){
    int lin = c*256 + tid;
    int kr = lin >> 4;
    int e4 = (lin & 15) * 4;
    float4 vv = *reinterpret_cast<const float4*>(&src[(size_t)kr*HSq + e4]);
    t[e4+0][kr] = (short)f2bf(vv.x*scl);
    t[e4+1][kr] = (short)f2bf(vv.y*scl);
    t[e4+2][kr] = (short)f2bf(vv.z*scl);
    t[e4+3][kr] = (short)f2bf(vv.w*scl);
  }
  __syncthreads();
  short* dst = Wdst + (size_t)h*HSq*Kc + (size_t)kt*64;
  #pragma unroll
  for (int c=0;c<4;c++){
    int lin = c*256 + tid;
    int er = lin >> 4;
    int k4 = (lin & 15) * 4;
    ushort4 o;
    o.x = (unsigned short)t[er][k4+0];
    o.y = (unsigned short)t[er][k4+1];
    o.z = (unsigned short)t[er][k4+2];
    o.w = (unsigned short)t[er][k4+3];
    *reinterpret_cast<ushort4*>(&dst[(size_t)er*Kc + k4]) = o;
  }
}

// ---------------- fused Q/K/V projection GEMM (one dispatch, grid (512,3)) -------
// 128x128 tile, BK=64, global_load_lds, M-stripe XCD swizzle. (R7 version, measured)
__global__ __launch_bounds__(256) void proj3_kernel(
    const short* __restrict__ qn, const short* __restrict__ kn, const short* __restrict__ vn,
    const short* __restrict__ wqt, const short* __restrict__ wkt, const short* __restrict__ wvt,
    short* __restrict__ qh, short* __restrict__ kh, short* __restrict__ vhT)
{
  const int z = blockIdx.y;
  const short* A  = (z==0) ? qn  : (z==1) ? kn  : vn;
  const short* BT = (z==0) ? wqt : (z==1) ? wkt : wvt;

  const int bid = blockIdx.x;
  const int c8_ = bid & 7, j = bid >> 3;
  const int bm = c8_*8 + (j & 7), bn = j >> 3;
  const int m0 = bm * 128;
  const int n0c = bn * 128;
  const int tid = threadIdx.x;
  const int lane = tid & 63, w = tid >> 6;
  const int wm = w >> 1, wn = w & 1;
  const int fr = lane & 15, fg = lane >> 4;

  __shared__ short As[128*64];
  __shared__ short Bs[128*64];

  f32x4 acc[4][4] = {};

  const int rowT = tid >> 3;
  const int inb  = (tid & 7) * 16;

  for (int kt = 0; kt < Kc/64; ++kt){
    const int k0 = kt*64;
    #pragma unroll
    for (int c=0;c<4;c++){
      int row = c*32 + rowT;
      int src = inb ^ ((row & 7) << 4);
      gl_lds16((const char*)(A  + (size_t)(m0  + row)*Kc + k0) + src,
               (char*)As + c*4096 + w*1024);
      gl_lds16((const char*)(BT + (size_t)(n0c + row)*Kc + k0) + src,
               (char*)Bs + c*4096 + w*1024);
    }
    __syncthreads();
    #pragma unroll
    for (int kk=0;kk<2;kk++){
      short8 af[4], bf8[4];
      #pragma unroll
      for (int mr=0;mr<4;mr++){
        int row = wm*64 + mr*16 + fr;
        int byt = row*128 + ((kk*64 + fg*16) ^ ((row & 7) << 4));
        af[mr] = *reinterpret_cast<const short8*>((const char*)As + byt);
      }
      #pragma unroll
      for (int nr=0;nr<4;nr++){
        int row = wn*64 + nr*16 + fr;
        int byt = row*128 + ((kk*64 + fg*16) ^ ((row & 7) << 4));
        bf8[nr] = *reinterpret_cast<const short8*>((const char*)Bs + byt);
      }
      #pragma unroll
      for (int mr=0;mr<4;mr++)
        #pragma unroll
        for (int nr=0;nr<4;nr++)
          acc[mr][nr] = __builtin_amdgcn_mfma_f32_16x16x32_bf16(af[mr], bf8[nr], acc[mr][nr], 0, 0, 0);
    }
    __syncthreads();
  }

  if (z == 2){
    #pragma unroll
    for (int mr=0;mr<4;mr++){
      #pragma unroll
      for (int nr=0;nr<4;nr++){
        int col = n0c + wn*64 + nr*16 + fr;
        int h = col >> 6, e = col & 63;
        int R = m0 + wm*64 + mr*16 + fg*4;
        int bb = R >> 11, sPos = R & (Sq-1);
        uint2 o;
        o.x = cvtpk(acc[mr][nr][0], acc[mr][nr][1]);
        o.y = cvtpk(acc[mr][nr][2], acc[mr][nr][3]);
        *reinterpret_cast<uint2*>(&vhT[(((size_t)bb*Hq + h)*HSq + e)*Sq + sPos]) = o;
      }
    }
  } else {
    short* outb = z ? kh : qh;
    #pragma unroll
    for (int mr=0;mr<4;mr++){
      #pragma unroll
      for (int nr=0;nr<4;nr++){
        int col = n0c + wn*64 + nr*16 + fr;
        int h = col >> 6, e = col & 63;
        #pragma unroll
        for (int r=0;r<4;r++){
          int R = m0 + wm*64 + mr*16 + fg*4 + r;
          int bb = R >> 11, sPos = R & (Sq-1);
          outb[(((size_t)bb*Hq + h)*Sq + sPos)*HSq + e] = (short)f2bf(acc[mr][nr][r]);
        }
      }
    }
  }
}

// ---------------- output projection GEMM (fp32 out + bias), R7 version ----------
__global__ __launch_bounds__(256) void gemmo_kernel(
    const short* __restrict__ A,
    const short* __restrict__ BT,
    const float* __restrict__ bias,
    float* __restrict__ outf)
{
  const int bid = blockIdx.x;
  const int c8_ = bid & 7, j = bid >> 3;
  const int bm = c8_*8 + (j & 7), bn = j >> 3;
  const int m0 = bm * 128;
  const int n0c = bn * 128;
  const int tid = threadIdx.x;
  const int lane = tid & 63, w = tid >> 6;
  const int wm = w >> 1, wn = w & 1;
  const int fr = lane & 15, fg = lane >> 4;

  __shared__ short As[128*64];
  __shared__ short Bs[128*64];

  f32x4 acc[4][4] = {};

  const int rowT = tid >> 3;
  const int inb  = (tid & 7) * 16;

  for (int kt = 0; kt < Kc/64; ++kt){
    const int k0 = kt*64;
    #pragma unroll
    for (int c=0;c<4;c++){
      int row = c*32 + rowT;
      int src = inb ^ ((row & 7) << 4);
      gl_lds16((const char*)(A  + (size_t)(m0  + row)*Kc + k0) + src,
               (char*)As + c*4096 + w*1024);
      gl_lds16((const char*)(BT + (size_t)(n0c + row)*Kc + k0) + src,
               (char*)Bs + c*4096 + w*1024);
    }
    __syncthreads();
    #pragma unroll
    for (int kk=0;kk<2;kk++){
      short8 af[4], bf8[4];
      #pragma unroll
      for (int mr=0;mr<4;mr++){
        int row = wm*64 + mr*16 + fr;
        int byt = row*128 + ((kk*64 + fg*16) ^ ((row & 7) << 4));
        af[mr] = *reinterpret_cast<const short8*>((const char*)As + byt);
      }
      #pragma unroll
      for (int nr=0;nr<4;nr++){
        int row = wn*64 + nr*16 + fr;
        int byt = row*128 + ((kk*64 + fg*16) ^ ((row & 7) << 4));
        bf8[nr] = *reinterpret_cast<const short8*>((const char*)Bs + byt);
      }
      #pragma unroll
      for (int mr=0;mr<4;mr++)
        #pragma unroll
        for (int nr=0;nr<4;nr++)
          acc[mr][nr] = __builtin_amdgcn_mfma_f32_16x16x32_bf16(af[mr], bf8[nr], acc[mr][nr], 0, 0, 0);
    }
    __syncthreads();
  }

  #pragma unroll
  for (int mr=0;mr<4;mr++){
    #pragma unroll
    for (int nr=0;nr<4;nr++){
      int col = n0c + wn*64 + nr*16 + fr;
      #pragma unroll
      for (int r=0;r<4;r++){
        int R = m0 + wm*64 + mr*16 + fg*4 + r;
        outf[(size_t)R*Dq + col] = acc[mr][nr][r] + bias[col];
      }
    }
  }
}

// ---------------- flash attention (causal), swapped-MFMA, pair-balanced ----------
// grid 512: jp = bid>>6 (0..7), block does qt=15-jp then qt=jp -> 36 kv-tiles each.
// (b,h) = bid&63 (XCD = g&7 keeps one head's K/V on one XCD's L2).
// lsum via ones-MFMA (idle matrix pipe), kv-loop unrolled x2 for compile-time buf.
__global__ __launch_bounds__(256, 4) void attn_kernel(
    const short* __restrict__ qh, const short* __restrict__ kh,
    const short* __restrict__ vhT, short* __restrict__ attO)
{
  const int bid = blockIdx.x;
  const int jp  = bid >> 6;           // 0..7
  const int g   = bid & 63;
  const int h = g & 15, b = g >> 4;
  const short* Q  = qh  + (((size_t)b*Hq + h)*Sq)*HSq;
  const short* K  = kh  + (((size_t)b*Hq + h)*Sq)*HSq;
  const short* VT = vhT + (((size_t)b*Hq + h)*HSq)*Sq;   // [e][s]
  const int tid = threadIdx.x, w = tid >> 6, lane = tid & 63;
  const int fr = lane & 15, fg = lane >> 4;

  __shared__ short KsB[2][64*64];     // [kv][d], source pre-swizzled, LDS linear
  __shared__ short VtB[2][64*64];     // [e][kv]
  __shared__ short Ps[4][32][76];     // per-wave P [q_local][k_local], conflict-free

  const int sRow = tid >> 3;
  const int swz  = ((tid & 7) << 4) ^ ((sRow & 7) << 4);
  const char* pK = (const char*)K  + (size_t)sRow*128      + swz;
  const char* pV = (const char*)VT + (size_t)sRow*(Sq*2)   + swz;

  // A-operand of all-ones for row-sum MFMA (bf16 1.0 = 0x3F80)
  short8 ones;
  #pragma unroll
  for (int i=0;i<8;i++) ones[i] = (short)0x3F80;

  for (int pass = 0; pass < 2; ++pass){
    const int qt = pass ? jp : (15 - jp);
    const int qbase = qt * 128;
    const int nkv = 2*qt + 2;          // always even

    short8 qa[2][2];
    #pragma unroll
    for (int mr=0;mr<2;mr++){
      const int qrow = qbase + w*32 + mr*16 + fr;
      #pragma unroll
      for (int kk=0;kk<2;kk++)
        qa[mr][kk] = *reinterpret_cast<const short8*>(&Q[(size_t)qrow*HSq + kk*32 + 8*fg]);
    }

    f32x4 accO[2][4] = {};    // [mr][e-block], lane: e=fg*4+r, q=fr
    f32x4 accL[2] = {};       // l per q=fr (all regs identical)

    // prologue: stage tile 0 into buf 0
    #pragma unroll
    for (int c=0;c<2;c++){
      gl_lds16(pK + c*4096,   (char*)KsB[0] + c*4096 + w*1024);
      gl_lds16(pV + c*131072, (char*)VtB[0] + c*4096 + w*1024);
    }
    __syncthreads();

    for (int kt0 = 0; kt0 < nkv; kt0 += 2){
      #pragma unroll
      for (int u = 0; u < 2; ++u){       // buf = u folds to literal after unroll
        const int kt = kt0 + u;
        const int buf = u;

        if (kt+1 < nkv){                 // prefetch next tile into other buffer
          const char* nK = pK + (size_t)(kt+1)*8192;
          const char* nV = pV + (size_t)(kt+1)*128;
          #pragma unroll
          for (int c=0;c<2;c++){
            gl_lds16(nK + c*4096,   (char*)KsB[buf^1] + c*4096 + w*1024);
            gl_lds16(nV + c*131072, (char*)VtB[buf^1] + c*4096 + w*1024);
          }
        }

        // ---- S^T = K Q^T : lane holds k = n0*16+fg*4+r, q = mr*16+fr
        f32x4 sfr[2][4] = {};
        __builtin_amdgcn_s_setprio(1);
        #pragma unroll
        for (int kk=0;kk<2;kk++){
          short8 kb[4];
          #pragma unroll
          for (int n0=0;n0<4;n0++){
            int row = n0*16 + fr;
            int byt = row*128 + ((((kk*4+fg) ^ (row & 7))) << 4);
            kb[n0] = *reinterpret_cast<const short8*>((const char*)KsB[buf] + byt);
          }
          #pragma unroll
          for (int mr=0;mr<2;mr++)
            #pragma unroll
            for (int n0=0;n0<4;n0++)
              sfr[mr][n0] = __builtin_amdgcn_mfma_f32_16x16x32_bf16(kb[n0], qa[mr][kk], sfr[mr][n0], 0, 0, 0);
        }
        __builtin_amdgcn_s_setprio(0);

        // ---- softmax-lite: p = 2^s (HW exp), mask on diagonal tiles, pk-pack
        #pragma unroll
        for (int mr=0;mr<2;mr++){
          const int qr = qbase + w*32 + mr*16 + fr;
          const bool needmask = (kt*64 + 63) > (qbase + w*32 + mr*16);
          #pragma unroll
          for (int n0=0;n0<4;n0++){
            float p0 = exp2hw(sfr[mr][n0][0]);
            float p1 = exp2hw(sfr[mr][n0][1]);
            float p2 = exp2hw(sfr[mr][n0][2]);
            float p3 = exp2hw(sfr[mr][n0][3]);
            if (needmask){
              int kc = kt*64 + n0*16 + fg*4;
              if (kc+0 > qr) p0 = 0.0f;
              if (kc+1 > qr) p1 = 0.0f;
              if (kc+2 > qr) p2 = 0.0f;
              if (kc+3 > qr) p3 = 0.0f;
            }
            uint2 u2;
            u2.x = cvtpk(p0, p1);
            u2.y = cvtpk(p2, p3);
            *reinterpret_cast<uint2*>(&Ps[w][mr*16 + fr][n0*16 + fg*4]) = u2;
          }
        }

        // ---- O^T += V^T P ; l += 1^T P (row-sum on the matrix pipe)
        __builtin_amdgcn_s_setprio(1);
        #pragma unroll
        for (int kk=0;kk<2;kk++){
          short8 pa[2], vb[4];
          #pragma unroll
          for (int mr=0;mr<2;mr++)
            pa[mr] = *reinterpret_cast<short8*>(&Ps[w][mr*16 + fr][kk*32 + 8*fg]);
          #pragma unroll
          for (int n0=0;n0<4;n0++){
            int row = n0*16 + fr;
            int byt = row*128 + ((((kk*4+fg) ^ (row & 7))) << 4);
            vb[n0] = *reinterpret_cast<const short8*>((const char*)VtB[buf] + byt);
          }
          #pragma unroll
          for (int mr=0;mr<2;mr++){
            #pragma unroll
            for (int n0=0;n0<4;n0++)
              accO[mr][n0] = __builtin_amdgcn_mfma_f32_16x16x32_bf16(vb[n0], pa[mr], accO[mr][n0], 0, 0, 0);
            accL[mr] = __builtin_amdgcn_mfma_f32_16x16x32_bf16(ones, pa[mr], accL[mr], 0, 0, 0);
          }
        }
        __builtin_amdgcn_s_setprio(0);

        __syncthreads();   // vmcnt drained: prefetched tile landed; buf readers done
      }
    }

    // ---- epilogue: l already lane-local (accL rows identical), pk-packed stores
    #pragma unroll
    for (int mr=0;mr<2;mr++){
      float inv = rcphw(accL[mr][0]);
      const int qr = qbase + w*32 + mr*16 + fr;
      short* orow = attO + ((size_t)b*Sq + qr)*Dq + h*HSq;
      #pragma unroll
      for (int n0=0;n0<4;n0++){
        uint2 u2;
        u2.x = cvtpk(accO[mr][n0][0] * inv, accO[mr][n0][1] * inv);
        u2.y = cvtpk(accO[mr][n0][2] * inv, accO[mr][n0][3] * inv);
        *reinterpret_cast<uint2*>(&orow[n0*16 + fg*4]) = u2;
      }
    }
    // next pass restages buf0; last barrier of the tile loop already synced all waves
  }
}

extern "C" void kernel_launch(void* const* d_in, const int* in_sizes, int n_in,
                              void* d_out, int out_size, void* d_ws, size_t ws_size,
                              hipStream_t stream){
  const float* v_in = (const float*)d_in[0];
  const float* k_in = (const float*)d_in[1];
  const float* q_in = (const float*)d_in[2];
  const float* ln_g = (const float*)d_in[4];
  const float* ln_b = (const float*)d_in[5];
  const float* Wq   = (const float*)d_in[6];
  const float* Wk   = (const float*)d_in[7];
  const float* Wv   = (const float*)d_in[8];
  const float* Wp   = (const float*)d_in[9];
  const float* bp   = (const float*)d_in[10];
  float* out = (float*)d_out;

  char* ws = (char*)d_ws;
  const size_t BSD  = (size_t)Bq*Sq*Dq;
  const size_t BSD2 = BSD * 2;
  short* vn  = (short*)(ws);
  short* kn  = (short*)(ws + BSD2);
  short* qn  = (short*)(ws + 2*BSD2);
  short* wqt = (short*)(ws + 3*BSD2);
  short* wkt = (short*)(ws + 3*BSD2 + 2097152);
  short* wvt = (short*)(ws + 3*BSD2 + 2*2097152);
  short* wpb = (short*)(ws + 3*BSD2 + 3*2097152);
  short* qh  = (short*)(ws + 3*BSD2 + 4*2097152);
  short* kh  = qh + BSD;
  short* vhT = kh + BSD;
  short* attO = vn;   // vn dead after v-projection

  ln3_kernel<<<dim3(Bq*Sq, 3), 256, 0, stream>>>(v_in, k_in, q_in, ln_g, ln_b, vn, kn, qn);

  trcvt3_kernel<<<dim3(16, Hq, 3), 256, 0, stream>>>(Wq, Wk, Wv, wqt, wkt, wvt);
  cvt_kernel<<<1024, 256, 0, stream>>>(Wp, wpb, 262144);

  proj3_kernel<<<dim3(512, 3), 256, 0, stream>>>(qn, kn, vn, wqt, wkt, wvt, qh, kh, vhT);

  attn_kernel<<<512, 256, 0, stream>>>(qh, kh, vhT, attO);

  gemmo_kernel<<<512, 256, 0, stream>>>(attO, wpb, bp, out);
}

// Round 11
// 182.294 us; speedup vs baseline: 1.1196x; 1.0221x over previous
//
#include <hip/hip_runtime.h>
#include <hip/hip_bf16.h>
#include <cstdint>
#include <cstddef>

#define Bq 4
#define Sq 2048
#define Dq 1024
#define Hq 16
#define HSq 64
#define Kc 1024

typedef short short8 __attribute__((ext_vector_type(8)));
typedef float f32x4 __attribute__((ext_vector_type(4)));

__device__ __forceinline__ unsigned short f2bf(float f){
  __hip_bfloat16 h = __float2bfloat16(f);
  return __builtin_bit_cast(unsigned short, h);
}

__device__ __forceinline__ float exp2hw(float x){
  float r;
  asm("v_exp_f32 %0, %1" : "=v"(r) : "v"(x));
  return r;
}
__device__ __forceinline__ unsigned cvtpk(float lo, float hi){
  unsigned r;
  asm("v_cvt_pk_bf16_f32 %0, %1, %2" : "=v"(r) : "v"(lo), "v"(hi));
  return r;
}
__device__ __forceinline__ float rcphw(float x){
  float r;
  asm("v_rcp_f32 %0, %1" : "=v"(r) : "v"(x));
  return r;
}

__device__ __forceinline__ void gl_lds16(const void* g, void* l){
  __builtin_amdgcn_global_load_lds((const __attribute__((address_space(1))) void*)(g),
                                   (__attribute__((address_space(3))) void*)(l), 16, 0, 0);
}

// ---------------- 3x LayerNorm (fp32 in) -> bf16 out, one dispatch ----------------
__global__ __launch_bounds__(256) void ln3_kernel(const float* __restrict__ v,
                                                  const float* __restrict__ k,
                                                  const float* __restrict__ q,
                                                  const float* __restrict__ g,
                                                  const float* __restrict__ bta,
                                                  short* __restrict__ vo,
                                                  short* __restrict__ ko,
                                                  short* __restrict__ qo){
  const int which = blockIdx.y;
  const float* x = (which==0) ? v : (which==1) ? k : q;
  short* out     = (which==0) ? vo : (which==1) ? ko : qo;
  const int row = blockIdx.x;
  const float* xr = x + (size_t)row * Dq;
  const int t = threadIdx.x;
  float4 vv = reinterpret_cast<const float4*>(xr)[t];
  float s  = vv.x + vv.y + vv.z + vv.w;
  float ss = vv.x*vv.x + vv.y*vv.y + vv.z*vv.z + vv.w*vv.w;
  #pragma unroll
  for (int o = 32; o >= 1; o >>= 1){ s += __shfl_xor(s, o); ss += __shfl_xor(ss, o); }
  __shared__ float red[8];
  const int wid = t >> 6;
  if ((t & 63) == 0){ red[wid] = s; red[4+wid] = ss; }
  __syncthreads();
  s  = red[0]+red[1]+red[2]+red[3];
  ss = red[4]+red[5]+red[6]+red[7];
  const float mu   = s * (1.0f/Dq);
  const float var  = ss * (1.0f/Dq) - mu*mu;
  const float rstd = rsqrtf(var + 1e-5f);
  float4 gv = reinterpret_cast<const float4*>(g)[t];
  float4 bv = reinterpret_cast<const float4*>(bta)[t];
  ushort4 o4;
  o4.x = f2bf((vv.x-mu)*rstd*gv.x + bv.x);
  o4.y = f2bf((vv.y-mu)*rstd*gv.y + bv.y);
  o4.z = f2bf((vv.z-mu)*rstd*gv.z + bv.z);
  o4.w = f2bf((vv.w-mu)*rstd*gv.w + bv.w);
  reinterpret_cast<ushort4*>(out + (size_t)row*Dq)[t] = o4;
}

// ---------------- fp32 -> bf16 cast (Wp row-major == B^T layout) ----------------
__global__ __launch_bounds__(256) void cvt_kernel(const float* __restrict__ in,
                                                  short* __restrict__ out, int n4){
  int i = blockIdx.x*256 + threadIdx.x;
  if (i < n4){
    float4 v = reinterpret_cast<const float4*>(in)[i];
    ushort4 o; o.x=f2bf(v.x); o.y=f2bf(v.y); o.z=f2bf(v.z); o.w=f2bf(v.w);
    reinterpret_cast<ushort4*>(out)[i] = o;
  }
}

// W [H][1024][64] fp32 -> WT [h*64+e][1024] bf16, all three in one dispatch.
// z==0 (Wq) is pre-scaled by D^-0.5 * log2(e).
__global__ __launch_bounds__(256) void trcvt3_kernel(const float* __restrict__ Wq,
                                                     const float* __restrict__ Wk,
                                                     const float* __restrict__ Wv,
                                                     short* __restrict__ wqt,
                                                     short* __restrict__ wkt,
                                                     short* __restrict__ wvt){
  const int z = blockIdx.z;
  const float* Wsrc = (z==0) ? Wq : (z==1) ? Wk : Wv;
  short* Wdst       = (z==0) ? wqt : (z==1) ? wkt : wvt;
  const float scl   = (z==0) ? (0.03125f * 1.44269504f) : 1.0f;
  const int h = blockIdx.y, kt = blockIdx.x, tid = threadIdx.x;
  __shared__ short t[64][68];
  const float* src = Wsrc + ((size_t)h*Kc + (size_t)kt*64) * HSq;
  #pragma unroll
  for (int c=0;c<4;c++){
    int lin = c*256 + tid;
    int kr = lin >> 4;
    int e4 = (lin & 15) * 4;
    float4 vv = *reinterpret_cast<const float4*>(&src[(size_t)kr*HSq + e4]);
    t[e4+0][kr] = (short)f2bf(vv.x*scl);
    t[e4+1][kr] = (short)f2bf(vv.y*scl);
    t[e4+2][kr] = (short)f2bf(vv.z*scl);
    t[e4+3][kr] = (short)f2bf(vv.w*scl);
  }
  __syncthreads();
  short* dst = Wdst + (size_t)h*HSq*Kc + (size_t)kt*64;
  #pragma unroll
  for (int c=0;c<4;c++){
    int lin = c*256 + tid;
    int er = lin >> 4;
    int k4 = (lin & 15) * 4;
    ushort4 o;
    o.x = (unsigned short)t[er][k4+0];
    o.y = (unsigned short)t[er][k4+1];
    o.z = (unsigned short)t[er][k4+2];
    o.w = (unsigned short)t[er][k4+3];
    *reinterpret_cast<ushort4*>(&dst[(size_t)er*Kc + k4]) = o;
  }
}

// ---------------- fused Q/K/V projection: 256x256 8-phase counted-vmcnt ----------
// grid (128, 3): bm = i&31, bn = i>>5 (all 4 n-blocks of one A-stripe on one XCD).
// 8 waves (2M x 4N), wave-tile 128x64 with SCATTERED A frag-rows m = i*32+wm*16 so
// phase p's A-quadrant lies in half p>>1. Per K-tile: p0 {vmcnt(2); barrier; read
// 8 B-frags + A-q0; stage B-h0(t+1); 16 MFMA}, p1 {read A-q1; stage B-h1; MFMA},
// p2 {vmcnt(4); barrier; read A-q2; stage A-h0; MFMA}, p3 {read A-q3; stage A-h1;
// MFMA}. Stages write buf^1; loads for t+1 stay in flight across t's compute.
__global__ __launch_bounds__(512, 2) void proj3_kernel(
    const short* __restrict__ qn, const short* __restrict__ kn, const short* __restrict__ vn,
    const short* __restrict__ wqt, const short* __restrict__ wkt, const short* __restrict__ wvt,
    short* __restrict__ qh, short* __restrict__ kh, short* __restrict__ vhT)
{
  const int z = blockIdx.y;
  const short* A  = (z==0) ? qn  : (z==1) ? kn  : vn;
  const short* BT = (z==0) ? wqt : (z==1) ? wkt : wvt;

  const int i = blockIdx.x;
  const int bm = i & 31, bn = i >> 5;
  const int m0 = bm * 256;
  const int n0c = bn * 256;
  const int tid = threadIdx.x;
  const int lane = tid & 63, w = tid >> 6;   // 8 waves
  const int wm = w >> 2, wn = w & 3;         // 2M x 4N
  const int fr = lane & 15, fg = lane >> 4;

  __shared__ short As[2*256*64];   // 64 KB: [buf][row 0..255][64], chunk-swizzled
  __shared__ short Bs[2*256*64];   // 64 KB

  f32x4 acc[8][4] = {};
  short8 bf[4][2];

  // staging geometry: thread covers row srow (+64 for 2nd call), 16B chunk (tid&7),
  // source pre-swizzled so LDS stays linear.
  const int srow = tid >> 3;                       // 0..63
  const int sw   = ((tid & 7) << 4) ^ ((srow & 7) << 4);
  const char* aB = (const char*)(A  + (size_t)(m0  + srow)*Kc) + sw;
  const char* bB = (const char*)(BT + (size_t)(n0c + srow)*Kc) + sw;

  // hh: 0=B-h0, 1=B-h1, 2=A-h0, 3=A-h1   (issue order per tile)
#define STAGE(t, hh, buf) do{                                              \
    const bool isB_ = (hh) < 2;                                            \
    const char* s_ = (isB_ ? bB : aB) + (size_t)((hh)&1)*(128*2048) + (size_t)(t)*128; \
    char* d_ = (char*)(isB_ ? (void*)Bs : (void*)As) + (buf)*32768 + ((hh)&1)*16384 + w*1024; \
    gl_lds16(s_, d_);                                                      \
    gl_lds16(s_ + 64*2048, d_ + 8192);                                     \
  }while(0)

#define READ_A(p, buf, af) do{                                             \
    _Pragma("unroll") for (int mm=0; mm<2; ++mm){                          \
      const int r_ = ((p)*2+mm)*32 + wm*16 + fr;                           \
      _Pragma("unroll") for (int kk=0; kk<2; ++kk){                        \
        const int byt_ = (buf)*32768 + r_*128 + (((kk*4+fg)^(r_&7))<<4);   \
        af[mm][kk] = *reinterpret_cast<const short8*>((const char*)As + byt_); \
      }}}while(0)

#define MFMA_P(p, af) do{                                                  \
    __builtin_amdgcn_s_setprio(1);                                         \
    _Pragma("unroll") for (int kk=0; kk<2; ++kk)                           \
      _Pragma("unroll") for (int mm=0; mm<2; ++mm)                         \
        _Pragma("unroll") for (int nr=0; nr<4; ++nr)                       \
          acc[(p)*2+mm][nr] = __builtin_amdgcn_mfma_f32_16x16x32_bf16(af[mm][kk], bf[nr][kk], acc[(p)*2+mm][nr], 0, 0, 0); \
    __builtin_amdgcn_s_setprio(0);                                         \
  }while(0)

#define DO_TILE(t, buf, HN) do{                                            \
    asm volatile("s_waitcnt vmcnt(2)" ::: "memory");                       \
    __builtin_amdgcn_s_barrier();                                          \
    _Pragma("unroll") for (int nr=0; nr<4; ++nr){                          \
      const int r_ = wn*64 + nr*16 + fr;                                   \
      _Pragma("unroll") for (int kk=0; kk<2; ++kk){                        \
        const int byt_ = (buf)*32768 + r_*128 + (((kk*4+fg)^(r_&7))<<4);   \
        bf[nr][kk] = *reinterpret_cast<const short8*>((const char*)Bs + byt_); \
      }}                                                                   \
    { short8 af[2][2]; READ_A(0, buf, af);                                 \
      if (HN) STAGE((t)+1, 0, (buf)^1);                                    \
      MFMA_P(0, af); }                                                     \
    { short8 af[2][2]; READ_A(1, buf, af);                                 \
      if (HN) STAGE((t)+1, 1, (buf)^1);                                    \
      MFMA_P(1, af); }                                                     \
    if (HN) { asm volatile("s_waitcnt vmcnt(4)" ::: "memory"); }           \
    else    { asm volatile("s_waitcnt vmcnt(0)" ::: "memory"); }           \
    __builtin_amdgcn_s_barrier();                                          \
    { short8 af[2][2]; READ_A(2, buf, af);                                 \
      if (HN) STAGE((t)+1, 2, (buf)^1);                                    \
      MFMA_P(2, af); }                                                     \
    { short8 af[2][2]; READ_A(3, buf, af);                                 \
      if (HN) STAGE((t)+1, 3, (buf)^1);                                    \
      MFMA_P(3, af); }                                                     \
  }while(0)

  // prologue: tile 0's four half-tiles into buf 0 (8 loads in flight)
  STAGE(0, 0, 0); STAGE(0, 1, 0); STAGE(0, 2, 0); STAGE(0, 3, 0);

  for (int t2 = 0; t2 < 7; ++t2){
    const int t = t2*2;
    DO_TILE(t,   0, true);
    DO_TILE(t+1, 1, true);
  }
  DO_TILE(14, 0, true);
  DO_TILE(15, 1, false);

#undef DO_TILE
#undef MFMA_P
#undef READ_A
#undef STAGE

  if (z == 2){
    #pragma unroll
    for (int mi=0; mi<8; ++mi){
      #pragma unroll
      for (int nr=0; nr<4; ++nr){
        int col = n0c + wn*64 + nr*16 + fr;
        int h = col >> 6, e = col & 63;
        int R = m0 + mi*32 + wm*16 + fg*4;
        int bb = R >> 11, sPos = R & (Sq-1);
        uint2 o;
        o.x = cvtpk(acc[mi][nr][0], acc[mi][nr][1]);
        o.y = cvtpk(acc[mi][nr][2], acc[mi][nr][3]);
        *reinterpret_cast<uint2*>(&vhT[(((size_t)bb*Hq + h)*HSq + e)*Sq + sPos]) = o;
      }
    }
  } else {
    short* outb = z ? kh : qh;
    #pragma unroll
    for (int mi=0; mi<8; ++mi){
      #pragma unroll
      for (int nr=0; nr<4; ++nr){
        int col = n0c + wn*64 + nr*16 + fr;
        int h = col >> 6, e = col & 63;
        #pragma unroll
        for (int r=0; r<4; ++r){
          int R = m0 + mi*32 + wm*16 + fg*4 + r;
          int bb = R >> 11, sPos = R & (Sq-1);
          outb[(((size_t)bb*Hq + h)*Sq + sPos)*HSq + e] = (short)f2bf(acc[mi][nr][r]);
        }
      }
    }
  }
}

// ---------------- output projection GEMM (fp32 out + bias), 128x128 ----------------
__global__ __launch_bounds__(256) void gemmo_kernel(
    const short* __restrict__ A,
    const short* __restrict__ BT,
    const float* __restrict__ bias,
    float* __restrict__ outf)
{
  const int bid = blockIdx.x;
  const int c8_ = bid & 7, j = bid >> 3;
  const int bm = c8_*8 + (j & 7), bn = j >> 3;
  const int m0 = bm * 128;
  const int n0c = bn * 128;
  const int tid = threadIdx.x;
  const int lane = tid & 63, w = tid >> 6;
  const int wm = w >> 1, wn = w & 1;
  const int fr = lane & 15, fg = lane >> 4;

  __shared__ short As[128*64];
  __shared__ short Bs[128*64];

  f32x4 acc[4][4] = {};

  const int rowT = tid >> 3;
  const int inb  = (tid & 7) * 16;

  for (int kt = 0; kt < Kc/64; ++kt){
    const int k0 = kt*64;
    #pragma unroll
    for (int c=0;c<4;c++){
      int row = c*32 + rowT;
      int src = inb ^ ((row & 7) << 4);
      gl_lds16((const char*)(A  + (size_t)(m0  + row)*Kc + k0) + src,
               (char*)As + c*4096 + w*1024);
      gl_lds16((const char*)(BT + (size_t)(n0c + row)*Kc + k0) + src,
               (char*)Bs + c*4096 + w*1024);
    }
    __syncthreads();
    #pragma unroll
    for (int kk=0;kk<2;kk++){
      short8 af[4], bf8[4];
      #pragma unroll
      for (int mr=0;mr<4;mr++){
        int row = wm*64 + mr*16 + fr;
        int byt = row*128 + ((kk*64 + fg*16) ^ ((row & 7) << 4));
        af[mr] = *reinterpret_cast<const short8*>((const char*)As + byt);
      }
      #pragma unroll
      for (int nr=0;nr<4;nr++){
        int row = wn*64 + nr*16 + fr;
        int byt = row*128 + ((kk*64 + fg*16) ^ ((row & 7) << 4));
        bf8[nr] = *reinterpret_cast<const short8*>((const char*)Bs + byt);
      }
      #pragma unroll
      for (int mr=0;mr<4;mr++)
        #pragma unroll
        for (int nr=0;nr<4;nr++)
          acc[mr][nr] = __builtin_amdgcn_mfma_f32_16x16x32_bf16(af[mr], bf8[nr], acc[mr][nr], 0, 0, 0);
    }
    __syncthreads();
  }

  #pragma unroll
  for (int mr=0;mr<4;mr++){
    #pragma unroll
    for (int nr=0;nr<4;nr++){
      int col = n0c + wn*64 + nr*16 + fr;
      #pragma unroll
      for (int r=0;r<4;r++){
        int R = m0 + wm*64 + mr*16 + fg*4 + r;
        outf[(size_t)R*Dq + col] = acc[mr][nr][r] + bias[col];
      }
    }
  }
}

// ---------------- flash attention (causal), swapped-MFMA, pair-balanced ----------
__global__ __launch_bounds__(256, 4) void attn_kernel(
    const short* __restrict__ qh, const short* __restrict__ kh,
    const short* __restrict__ vhT, short* __restrict__ attO)
{
  const int bid = blockIdx.x;
  const int jp  = bid >> 6;           // 0..7
  const int g   = bid & 63;
  const int h = g & 15, b = g >> 4;
  const short* Q  = qh  + (((size_t)b*Hq + h)*Sq)*HSq;
  const short* K  = kh  + (((size_t)b*Hq + h)*Sq)*HSq;
  const short* VT = vhT + (((size_t)b*Hq + h)*HSq)*Sq;   // [e][s]
  const int tid = threadIdx.x, w = tid >> 6, lane = tid & 63;
  const int fr = lane & 15, fg = lane >> 4;

  __shared__ short KsB[2][64*64];
  __shared__ short VtB[2][64*64];
  __shared__ short Ps[4][32][76];

  const int sRow = tid >> 3;
  const int swz  = ((tid & 7) << 4) ^ ((sRow & 7) << 4);
  const char* pK = (const char*)K  + (size_t)sRow*128      + swz;
  const char* pV = (const char*)VT + (size_t)sRow*(Sq*2)   + swz;

  short8 ones;
  #pragma unroll
  for (int ii=0;ii<8;ii++) ones[ii] = (short)0x3F80;

  for (int pass = 0; pass < 2; ++pass){
    const int qt = pass ? jp : (15 - jp);
    const int qbase = qt * 128;
    const int nkv = 2*qt + 2;

    short8 qa[2][2];
    #pragma unroll
    for (int mr=0;mr<2;mr++){
      const int qrow = qbase + w*32 + mr*16 + fr;
      #pragma unroll
      for (int kk=0;kk<2;kk++)
        qa[mr][kk] = *reinterpret_cast<const short8*>(&Q[(size_t)qrow*HSq + kk*32 + 8*fg]);
    }

    f32x4 accO[2][4] = {};
    f32x4 accL[2] = {};

    #pragma unroll
    for (int c=0;c<2;c++){
      gl_lds16(pK + c*4096,   (char*)KsB[0] + c*4096 + w*1024);
      gl_lds16(pV + c*131072, (char*)VtB[0] + c*4096 + w*1024);
    }
    __syncthreads();

    for (int kt0 = 0; kt0 < nkv; kt0 += 2){
      #pragma unroll
      for (int u = 0; u < 2; ++u){
        const int kt = kt0 + u;
        const int buf = u;

        if (kt+1 < nkv){
          const char* nK = pK + (size_t)(kt+1)*8192;
          const char* nV = pV + (size_t)(kt+1)*128;
          #pragma unroll
          for (int c=0;c<2;c++){
            gl_lds16(nK + c*4096,   (char*)KsB[buf^1] + c*4096 + w*1024);
            gl_lds16(nV + c*131072, (char*)VtB[buf^1] + c*4096 + w*1024);
          }
        }

        f32x4 sfr[2][4] = {};
        __builtin_amdgcn_s_setprio(1);
        #pragma unroll
        for (int kk=0;kk<2;kk++){
          short8 kb[4];
          #pragma unroll
          for (int n0=0;n0<4;n0++){
            int row = n0*16 + fr;
            int byt = row*128 + ((((kk*4+fg) ^ (row & 7))) << 4);
            kb[n0] = *reinterpret_cast<const short8*>((const char*)KsB[buf] + byt);
          }
          #pragma unroll
          for (int mr=0;mr<2;mr++)
            #pragma unroll
            for (int n0=0;n0<4;n0++)
              sfr[mr][n0] = __builtin_amdgcn_mfma_f32_16x16x32_bf16(kb[n0], qa[mr][kk], sfr[mr][n0], 0, 0, 0);
        }
        __builtin_amdgcn_s_setprio(0);

        #pragma unroll
        for (int mr=0;mr<2;mr++){
          const int qr = qbase + w*32 + mr*16 + fr;
          const bool needmask = (kt*64 + 63) > (qbase + w*32 + mr*16);
          #pragma unroll
          for (int n0=0;n0<4;n0++){
            float p0 = exp2hw(sfr[mr][n0][0]);
            float p1 = exp2hw(sfr[mr][n0][1]);
            float p2 = exp2hw(sfr[mr][n0][2]);
            float p3 = exp2hw(sfr[mr][n0][3]);
            if (needmask){
              int kc = kt*64 + n0*16 + fg*4;
              if (kc+0 > qr) p0 = 0.0f;
              if (kc+1 > qr) p1 = 0.0f;
              if (kc+2 > qr) p2 = 0.0f;
              if (kc+3 > qr) p3 = 0.0f;
            }
            uint2 u2;
            u2.x = cvtpk(p0, p1);
            u2.y = cvtpk(p2, p3);
            *reinterpret_cast<uint2*>(&Ps[w][mr*16 + fr][n0*16 + fg*4]) = u2;
          }
        }

        __builtin_amdgcn_s_setprio(1);
        #pragma unroll
        for (int kk=0;kk<2;kk++){
          short8 pa[2], vb[4];
          #pragma unroll
          for (int mr=0;mr<2;mr++)
            pa[mr] = *reinterpret_cast<short8*>(&Ps[w][mr*16 + fr][kk*32 + 8*fg]);
          #pragma unroll
          for (int n0=0;n0<4;n0++){
            int row = n0*16 + fr;
            int byt = row*128 + ((((kk*4+fg) ^ (row & 7))) << 4);
            vb[n0] = *reinterpret_cast<const short8*>((const char*)VtB[buf] + byt);
          }
          #pragma unroll
          for (int mr=0;mr<2;mr++){
            #pragma unroll
            for (int n0=0;n0<4;n0++)
              accO[mr][n0] = __builtin_amdgcn_mfma_f32_16x16x32_bf16(vb[n0], pa[mr], accO[mr][n0], 0, 0, 0);
            accL[mr] = __builtin_amdgcn_mfma_f32_16x16x32_bf16(ones, pa[mr], accL[mr], 0, 0, 0);
          }
        }
        __builtin_amdgcn_s_setprio(0);

        __syncthreads();
      }
    }

    #pragma unroll
    for (int mr=0;mr<2;mr++){
      float inv = rcphw(accL[mr][0]);
      const int qr = qbase + w*32 + mr*16 + fr;
      short* orow = attO + ((size_t)b*Sq + qr)*Dq + h*HSq;
      #pragma unroll
      for (int n0=0;n0<4;n0++){
        uint2 u2;
        u2.x = cvtpk(accO[mr][n0][0] * inv, accO[mr][n0][1] * inv);
        u2.y = cvtpk(accO[mr][n0][2] * inv, accO[mr][n0][3] * inv);
        *reinterpret_cast<uint2*>(&orow[n0*16 + fg*4]) = u2;
      }
    }
  }
}

extern "C" void kernel_launch(void* const* d_in, const int* in_sizes, int n_in,
                              void* d_out, int out_size, void* d_ws, size_t ws_size,
                              hipStream_t stream){
  const float* v_in = (const float*)d_in[0];
  const float* k_in = (const float*)d_in[1];
  const float* q_in = (const float*)d_in[2];
  const float* ln_g = (const float*)d_in[4];
  const float* ln_b = (const float*)d_in[5];
  const float* Wq   = (const float*)d_in[6];
  const float* Wk   = (const float*)d_in[7];
  const float* Wv   = (const float*)d_in[8];
  const float* Wp   = (const float*)d_in[9];
  const float* bp   = (const float*)d_in[10];
  float* out = (float*)d_out;

  char* ws = (char*)d_ws;
  const size_t BSD  = (size_t)Bq*Sq*Dq;
  const size_t BSD2 = BSD * 2;
  short* vn  = (short*)(ws);
  short* kn  = (short*)(ws + BSD2);
  short* qn  = (short*)(ws + 2*BSD2);
  short* wqt = (short*)(ws + 3*BSD2);
  short* wkt = (short*)(ws + 3*BSD2 + 2097152);
  short* wvt = (short*)(ws + 3*BSD2 + 2*2097152);
  short* wpb = (short*)(ws + 3*BSD2 + 3*2097152);
  short* qh  = (short*)(ws + 3*BSD2 + 4*2097152);
  short* kh  = qh + BSD;
  short* vhT = kh + BSD;
  short* attO = vn;   // vn dead after v-projection

  ln3_kernel<<<dim3(Bq*Sq, 3), 256, 0, stream>>>(v_in, k_in, q_in, ln_g, ln_b, vn, kn, qn);

  trcvt3_kernel<<<dim3(16, Hq, 3), 256, 0, stream>>>(Wq, Wk, Wv, wqt, wkt, wvt);
  cvt_kernel<<<1024, 256, 0, stream>>>(Wp, wpb, 262144);

  proj3_kernel<<<dim3(128, 3), 512, 0, stream>>>(qn, kn, vn, wqt, wkt, wvt, qh, kh, vhT);

  attn_kernel<<<512, 256, 0, stream>>>(qh, kh, vhT, attO);

  gemmo_kernel<<<512, 256, 0, stream>>>(attO, wpb, bp, out);
}